// Round 7
// baseline (585.502 us; speedup 1.0000x reference)
//
#include <hip/hip_runtime.h>

#define LL 2048
#define HH 2048
#define EE 4096
#define NS 16
#define RR 128
#define CT 32            // chunk timesteps
#define NC (LL / CT)     // 64 chunks
#define BM 128
#define BN 128
#define BK 64

typedef __bf16 bf16x8 __attribute__((ext_vector_type(8)));
typedef float f32x4 __attribute__((ext_vector_type(4)));

__device__ __forceinline__ unsigned short f2bf(float f) {
  union { float f; unsigned int u; } v; v.f = f;
  unsigned int r = v.u + 0x7fffu + ((v.u >> 16) & 1u);
  return (unsigned short)(r >> 16);
}

__device__ __forceinline__ float bf2f(unsigned short u) {
  union { unsigned int i; float f; } v;
  v.i = ((unsigned int)u) << 16;
  return v.f;
}

__device__ __forceinline__ void async_cp16(const unsigned short* g,
                                           unsigned short* l) {
  __builtin_amdgcn_global_load_lds(
      (const __attribute__((address_space(1))) unsigned int*)g,
      (__attribute__((address_space(3))) unsigned int*)l, 16, 0, 0);
}

// ---------------- fp32 -> bf16 cast (vectorized x4) ----------------
__global__ void cast_bf16_k(const float* __restrict__ in,
                            unsigned short* __restrict__ out, int n4) {
  int i = blockIdx.x * blockDim.x + threadIdx.x;
  if (i >= n4) return;
  float4 v = reinterpret_cast<const float4*>(in)[i];
  ushort4 o;
  o.x = f2bf(v.x); o.y = f2bf(v.y); o.z = f2bf(v.z); o.w = f2bf(v.w);
  reinterpret_cast<ushort4*>(out)[i] = o;
}

// ---------------- zero fill (float4) ----------------
__global__ void zero_k(float* __restrict__ p, int n4) {
  int i = blockIdx.x * blockDim.x + threadIdx.x;
  if (i >= n4) return;
  float4 z; z.x = z.y = z.z = z.w = 0.0f;
  reinterpret_cast<float4*>(p)[i] = z;
}

// ============ LDS-staged bf16 BT-GEMM: C[M,N] = A[M,K] * B[N,K]^T ============
// XCD swizzle: tnInner = bid&7 keeps one B-tile L2-resident per XCD.
// EPI (compile-time): 1 = f32 atomicAdd (split-K)
//                     2 = in_proj: cols<EE -> f32 auxF; cols>=EE -> silu bf16 auxB
//                     4 = +bias[col], softplus, bf16 store to auxB
template <int EPI>
__global__ __launch_bounds__(256) void gemm_lds_t(
    const unsigned short* __restrict__ A,
    const unsigned short* __restrict__ B,
    float* __restrict__ C,
    int M, int N, int K, int tilesM, int splitk,
    const float* __restrict__ bias, float* __restrict__ auxF,
    unsigned short* __restrict__ auxB) {
  __shared__ __align__(16) unsigned short As[BM * BK];
  __shared__ __align__(16) unsigned short Bs[BN * BK];

  int bid = blockIdx.x;
  int tnInner = bid & 7;
  int rest = bid >> 3;
  int tm = rest % tilesM;
  int tnOuter = rest / tilesM;
  int tn = tnOuter * 8 + tnInner;

  int Kslice = K / splitk;
  int k_begin = blockIdx.y * Kslice;
  int k_end = k_begin + Kslice;

  int tid = threadIdx.x;
  int lane = tid & 63;
  int wave = tid >> 6;
  int wm = wave & 1, wn = wave >> 1;
  int m16 = lane & 15, quad = lane >> 4;

  const unsigned short* Ab = A + (size_t)tm * BM * K;
  const unsigned short* Bb = B + (size_t)tn * BN * K;

  int srow[4], sgcb[4];
#pragma unroll
  for (int it = 0; it < 4; ++it) {
    int blk = it * 256 + tid;
    srow[it] = blk >> 3;
    sgcb[it] = (blk & 7) ^ (srow[it] & 7);
  }
  int ldsbase = (tid & ~63) * 8;  // wave-uniform, in ushort units

  f32x4 acc[4][4];
#pragma unroll
  for (int i = 0; i < 4; ++i)
#pragma unroll
    for (int j = 0; j < 4; ++j)
#pragma unroll
      for (int t = 0; t < 4; ++t) acc[i][j][t] = 0.0f;

  for (int k0 = k_begin; k0 < k_end; k0 += BK) {
    __syncthreads();
#pragma unroll
    for (int it = 0; it < 4; ++it)
      async_cp16(Ab + (size_t)srow[it] * K + k0 + sgcb[it] * 8,
                 &As[it * 2048 + ldsbase]);
#pragma unroll
    for (int it = 0; it < 4; ++it)
      async_cp16(Bb + (size_t)srow[it] * K + k0 + sgcb[it] * 8,
                 &Bs[it * 2048 + ldsbase]);
    __syncthreads();
#pragma unroll
    for (int kk = 0; kk < 2; ++kk) {
      bf16x8 a[4], b[4];
#pragma unroll
      for (int i = 0; i < 4; ++i) {
        int rr = wm * 64 + i * 16 + m16;
        int cb = (kk << 2) + quad;
        a[i] = *reinterpret_cast<const bf16x8*>(
            &As[rr * BK + ((cb ^ (rr & 7)) << 3)]);
      }
#pragma unroll
      for (int j = 0; j < 4; ++j) {
        int rr = wn * 64 + j * 16 + m16;
        int cb = (kk << 2) + quad;
        b[j] = *reinterpret_cast<const bf16x8*>(
            &Bs[rr * BK + ((cb ^ (rr & 7)) << 3)]);
      }
#pragma unroll
      for (int i = 0; i < 4; ++i)
#pragma unroll
        for (int j = 0; j < 4; ++j)
          acc[i][j] =
              __builtin_amdgcn_mfma_f32_16x16x32_bf16(a[i], b[j], acc[i][j], 0, 0, 0);
    }
  }

  int rowB = tm * BM + wm * 64;
  int colB = tn * BN + wn * 64;
  if constexpr (EPI == 1) {
#pragma unroll
    for (int i = 0; i < 4; ++i)
#pragma unroll
      for (int j = 0; j < 4; ++j) {
        int col = colB + j * 16 + m16;
        int row0 = rowB + i * 16 + quad * 4;
#pragma unroll
        for (int t = 0; t < 4; ++t)
          atomicAdd(&C[(size_t)(row0 + t) * N + col], acc[i][j][t]);
      }
  } else if constexpr (EPI == 2) {
    if (colB < EE) {
#pragma unroll
      for (int i = 0; i < 4; ++i)
#pragma unroll
        for (int j = 0; j < 4; ++j) {
          int col = colB + j * 16 + m16;
          int row0 = rowB + i * 16 + quad * 4;
#pragma unroll
          for (int t = 0; t < 4; ++t)
            auxF[(size_t)(row0 + t) * EE + col] = acc[i][j][t];
        }
    } else {
#pragma unroll
      for (int i = 0; i < 4; ++i)
#pragma unroll
        for (int j = 0; j < 4; ++j) {
          int cg = colB + j * 16 + m16 - EE;
          int row0 = rowB + i * 16 + quad * 4;
#pragma unroll
          for (int t = 0; t < 4; ++t) {
            float v = acc[i][j][t];
            float s = v / (1.0f + __expf(-v));
            auxB[(size_t)(row0 + t) * EE + cg] = f2bf(s);
          }
        }
    }
  } else {  // EPI == 4: bias + softplus -> bf16
#pragma unroll
    for (int i = 0; i < 4; ++i)
#pragma unroll
      for (int j = 0; j < 4; ++j) {
        int col = colB + j * 16 + m16;
        float bv = bias[col];
        int row0 = rowB + i * 16 + quad * 4;
#pragma unroll
        for (int t = 0; t < 4; ++t) {
          float x = acc[i][j][t] + bv;
          float sp = (x > 20.0f) ? x : log1pf(__expf(x));
          auxB[(size_t)(row0 + t) * EE + col] = f2bf(sp);
        }
      }
  }
}

// ------------- direct (no-LDS) BT-GEMM for skinny N (x_proj) -------------
__global__ __launch_bounds__(256) void gemm_bt(
    const unsigned short* __restrict__ A,
    const unsigned short* __restrict__ B,
    float* __restrict__ C,
    int M, int N, int K, int tilesN, int splitk) {
  int bid = blockIdx.x;
  int groupSize = 8 * tilesN;
  int g = bid / groupSize, r = bid % groupSize;
  int tm = g * 8 + (r & 7);
  int tn = r >> 3;

  int Kslice = K / splitk;
  int k_begin = blockIdx.y * Kslice;
  int k_end = k_begin + Kslice;

  int tid = threadIdx.x;
  int wave = tid >> 6, lane = tid & 63;
  int wm = wave & 1, wn = wave >> 1;
  int m16 = lane & 15, quad = lane >> 4;
  int rowBase = tm * 64 + wm * 32;
  int colBase = tn * 128 + wn * 64;

  const unsigned short* a0p = A + (size_t)(rowBase + m16) * K + quad * 8;
  const unsigned short* a1p = A + (size_t)(rowBase + 16 + m16) * K + quad * 8;
  const unsigned short* bp[4];
  bool bok[4];
#pragma unroll
  for (int j = 0; j < 4; ++j) {
    int col = colBase + j * 16 + m16;
    bok[j] = (col < N);
    bp[j] = B + (size_t)(bok[j] ? col : 0) * K + quad * 8;
  }

  f32x4 acc[2][4];
#pragma unroll
  for (int i = 0; i < 2; ++i)
#pragma unroll
    for (int j = 0; j < 4; ++j)
#pragma unroll
      for (int t = 0; t < 4; ++t) acc[i][j][t] = 0.0f;

  bf16x8 zero8;
#pragma unroll
  for (int t = 0; t < 8; ++t) zero8[t] = (__bf16)0.0f;

  for (int k = k_begin; k < k_end; k += 32) {
    bf16x8 a0 = *reinterpret_cast<const bf16x8*>(a0p + k);
    bf16x8 a1 = *reinterpret_cast<const bf16x8*>(a1p + k);
    bf16x8 b[4];
#pragma unroll
    for (int j = 0; j < 4; ++j)
      b[j] = bok[j] ? *reinterpret_cast<const bf16x8*>(bp[j] + k) : zero8;
#pragma unroll
    for (int j = 0; j < 4; ++j) {
      acc[0][j] = __builtin_amdgcn_mfma_f32_16x16x32_bf16(a0, b[j], acc[0][j], 0, 0, 0);
      acc[1][j] = __builtin_amdgcn_mfma_f32_16x16x32_bf16(a1, b[j], acc[1][j], 0, 0, 0);
    }
  }

#pragma unroll
  for (int i = 0; i < 2; ++i)
#pragma unroll
    for (int j = 0; j < 4; ++j) {
      int col = colBase + j * 16 + m16;
      if (col >= N) continue;
      int row0 = rowBase + i * 16 + quad * 4;
      if (splitk == 1) {
#pragma unroll
        for (int t = 0; t < 4; ++t)
          C[(size_t)(row0 + t) * N + col] = acc[i][j][t];
      } else {
#pragma unroll
        for (int t = 0; t < 4; ++t)
          atomicAdd(&C[(size_t)(row0 + t) * N + col], acc[i][j][t]);
      }
    }
}

// ------- depthwise causal conv (K=4) + bias + silu, register window -------
__global__ __launch_bounds__(256) void conv_silu_k(
    const float* __restrict__ projh, const float* __restrict__ cw,
    const float* __restrict__ cb, unsigned short* __restrict__ hb) {
  int e = blockIdx.x * 256 + threadIdx.x;
  int l0 = blockIdx.y * 16;
  float w0 = cw[e * 4 + 0], w1 = cw[e * 4 + 1];
  float w2 = cw[e * 4 + 2], w3 = cw[e * 4 + 3];
  float bias = cb[e];
  float xm3 = (l0 >= 3) ? projh[(size_t)(l0 - 3) * EE + e] : 0.0f;
  float xm2 = (l0 >= 2) ? projh[(size_t)(l0 - 2) * EE + e] : 0.0f;
  float xm1 = (l0 >= 1) ? projh[(size_t)(l0 - 1) * EE + e] : 0.0f;
#pragma unroll
  for (int t = 0; t < 16; ++t) {
    int l = l0 + t;
    float x0 = projh[(size_t)l * EE + e];
    float acc = bias + w0 * xm3 + w1 * xm2 + w2 * xm1 + w3 * x0;
    float s = acc / (1.0f + __expf(-acc));
    hb[(size_t)l * EE + e] = f2bf(s);
    xm3 = xm2; xm2 = xm1; xm1 = x0;
  }
}

// ---------------- extract dt rows of ssm -> bf16 [L,128] ----------------
__global__ void dtcast_k(const float* __restrict__ ssm,
                         unsigned short* __restrict__ dtin, int n) {
  int i = blockIdx.x * blockDim.x + threadIdx.x;
  if (i >= n) return;
  int l = i >> 7, r = i & 127;
  dtin[i] = f2bf(ssm[l * 160 + r]);
}

// ================= chunked selective scan (16 states per thread) ===========
// dA = exp2(dt * Aa2[n]) with Aa2 = -exp(A_log)*log2e  (one mul + one v_exp)
__global__ __launch_bounds__(256) void scan_partA(
    const unsigned short* __restrict__ dtb, const unsigned short* __restrict__ hb,
    const float* __restrict__ ssm, const float* __restrict__ A_log,
    float* __restrict__ P, float* __restrict__ S) {
  int e = blockIdx.y * 256 + threadIdx.x;
  int c = blockIdx.x;
  float Aa[16];
#pragma unroll
  for (int q = 0; q < 4; ++q) {
    float4 a = reinterpret_cast<const float4*>(&A_log[(size_t)e * NS])[q];
    Aa[q * 4 + 0] = -__expf(a.x) * 1.44269504f;
    Aa[q * 4 + 1] = -__expf(a.y) * 1.44269504f;
    Aa[q * 4 + 2] = -__expf(a.z) * 1.44269504f;
    Aa[q * 4 + 3] = -__expf(a.w) * 1.44269504f;
  }
  float s[16], p[16];
#pragma unroll
  for (int n = 0; n < 16; ++n) { s[n] = 0.0f; p[n] = 1.0f; }
  int l0 = c * CT;
#pragma unroll 2
  for (int t = 0; t < CT; ++t) {
    int l = l0 + t;
    size_t o = (size_t)l * EE + e;
    float dtv = bf2f(dtb[o]);
    float hv = bf2f(hb[o]);
    float Bv[16];
#pragma unroll
    for (int q = 0; q < 4; ++q)
      *reinterpret_cast<float4*>(&Bv[q * 4]) =
          reinterpret_cast<const float4*>(&ssm[(size_t)l * 160 + 128])[q];
    float z = dtv * hv;
#pragma unroll
    for (int n = 0; n < 16; ++n) {
      float dA = __builtin_amdgcn_exp2f(dtv * Aa[n]);
      s[n] = s[n] * dA + z * Bv[n];
      p[n] *= dA;
    }
  }
  size_t base = ((size_t)c * EE + e) * NS;
#pragma unroll
  for (int q = 0; q < 4; ++q) {
    reinterpret_cast<float4*>(&P[base])[q] = *reinterpret_cast<float4*>(&p[q * 4]);
    reinterpret_cast<float4*>(&S[base])[q] = *reinterpret_cast<float4*>(&s[q * 4]);
  }
}

__global__ __launch_bounds__(256) void scan_chunkB(
    const float* __restrict__ P, float* __restrict__ S) {
  int gidx = blockIdx.x * 256 + threadIdx.x;
  float s = 0.0f;
  float pv = P[gidx], sv = S[gidx];
  for (int c = 0; c < NC; ++c) {
    float pn = 0.0f, sn = 0.0f;
    if (c + 1 < NC) {
      size_t i2 = (size_t)(c + 1) * (EE * NS) + gidx;
      pn = P[i2];
      sn = S[i2];
    }
    float s_next = s * pv + sv;
    S[(size_t)c * (EE * NS) + gidx] = s;
    s = s_next;
    pv = pn; sv = sn;
  }
}

__global__ __launch_bounds__(256) void scan_partC(
    const unsigned short* __restrict__ dtb, const unsigned short* __restrict__ hb,
    const float* __restrict__ ssm, const float* __restrict__ A_log,
    const float* __restrict__ Dp, const unsigned short* __restrict__ sg,
    const float* __restrict__ Sinit, unsigned short* __restrict__ yb) {
  int e = blockIdx.y * 256 + threadIdx.x;
  int c = blockIdx.x;
  float Aa[16];
#pragma unroll
  for (int q = 0; q < 4; ++q) {
    float4 a = reinterpret_cast<const float4*>(&A_log[(size_t)e * NS])[q];
    Aa[q * 4 + 0] = -__expf(a.x) * 1.44269504f;
    Aa[q * 4 + 1] = -__expf(a.y) * 1.44269504f;
    Aa[q * 4 + 2] = -__expf(a.z) * 1.44269504f;
    Aa[q * 4 + 3] = -__expf(a.w) * 1.44269504f;
  }
  float Dv = Dp[e];
  float s[16];
  size_t base = ((size_t)c * EE + e) * NS;
#pragma unroll
  for (int q = 0; q < 4; ++q)
    *reinterpret_cast<float4*>(&s[q * 4]) =
        reinterpret_cast<const float4*>(&Sinit[base])[q];
  int l0 = c * CT;
#pragma unroll 2
  for (int t = 0; t < CT; ++t) {
    int l = l0 + t;
    size_t o = (size_t)l * EE + e;
    float dtv = bf2f(dtb[o]);
    float hv = bf2f(hb[o]);
    float Bv[16], Cv[16];
#pragma unroll
    for (int q = 0; q < 4; ++q) {
      *reinterpret_cast<float4*>(&Bv[q * 4]) =
          reinterpret_cast<const float4*>(&ssm[(size_t)l * 160 + 128])[q];
      *reinterpret_cast<float4*>(&Cv[q * 4]) =
          reinterpret_cast<const float4*>(&ssm[(size_t)l * 160 + 144])[q];
    }
    float z = dtv * hv;
    float y = 0.0f;
#pragma unroll
    for (int n = 0; n < 16; ++n) {
      float dA = __builtin_amdgcn_exp2f(dtv * Aa[n]);
      s[n] = s[n] * dA + z * Bv[n];
      y += s[n] * Cv[n];
    }
    float gv = bf2f(sg[o]);  // pre-activated silu(gate)
    float yv = (y + hv * Dv) * gv;
    yb[o] = f2bf(yv);
  }
}

extern "C" void kernel_launch(void* const* d_in, const int* in_sizes, int n_in,
                              void* d_out, int out_size, void* d_ws, size_t ws_size,
                              hipStream_t stream) {
  const float* hs   = (const float*)d_in[0];
  const float* w1   = (const float*)d_in[1];
  const float* cw   = (const float*)d_in[2];
  const float* cb   = (const float*)d_in[3];
  const float* xw   = (const float*)d_in[4];
  const float* dtw  = (const float*)d_in[5];
  const float* dtb  = (const float*)d_in[6];
  const float* Alog = (const float*)d_in[7];
  const float* Dp   = (const float*)d_in[8];
  const float* ow   = (const float*)d_in[9];
  float* out = (float*)d_out;

  char* ws = (char*)d_ws;
  size_t off = 0;
  auto alloc = [&](size_t b) {
    char* p = ws + off;
    off += (b + 255) & ~(size_t)255;
    return p;
  };
  float* projh = (float*)alloc((size_t)LL * EE * 4);                 // 33.5 MB
  unsigned short* sg  = (unsigned short*)alloc((size_t)LL * EE * 2); // 16.8 MB
  unsigned short* hb  = (unsigned short*)alloc((size_t)LL * EE * 2); // 16.8 MB
  unsigned short* dtb_buf = (unsigned short*)alloc((size_t)LL * EE * 2); // 16.8 MB
  unsigned short* w1b = (unsigned short*)alloc((size_t)2 * EE * HH * 2); // 33.5 MB
  unsigned short* hsb = (unsigned short*)alloc((size_t)LL * HH * 2);
  unsigned short* yb  = (unsigned short*)alloc((size_t)LL * EE * 2);
  unsigned short* owb = (unsigned short*)alloc((size_t)HH * EE * 2);
  unsigned short* xwb = (unsigned short*)alloc((size_t)160 * EE * 2);
  float* ssm = (float*)alloc((size_t)LL * 160 * 4);
  unsigned short* dtin = (unsigned short*)alloc((size_t)LL * RR * 2);
  unsigned short* dtwb = (unsigned short*)alloc((size_t)EE * RR * 2);
  float* Pbuf = (float*)alloc((size_t)NC * EE * NS * 4);             // 16.8 MB
  float* Sbuf = (float*)alloc((size_t)NC * EE * NS * 4);             // 16.8 MB

  auto cast = [&](const float* in, unsigned short* o, int nelem) {
    int n4 = nelem / 4;
    cast_bf16_k<<<(n4 + 255) / 256, 256, 0, stream>>>(in, o, n4);
  };
  cast(hs, hsb, LL * HH);
  cast(w1, w1b, 2 * EE * HH);
  cast(xw, xwb, 160 * EE);
  cast(dtw, dtwb, EE * RR);
  cast(ow, owb, HH * EE);
  // zero accumulation targets for split-K atomics
  zero_k<<<(LL * 160 / 4 + 255) / 256, 256, 0, stream>>>(ssm, LL * 160 / 4);
  zero_k<<<(LL * HH / 4 + 255) / 256, 256, 0, stream>>>(out, LL * HH / 4);

  // 1) proj = hs @ in_proj_w^T [2048, 8192]; epilogue: h -> projh f32,
  //    gate -> silu -> sg bf16
  {
    int tilesN = (2 * EE) / BN, tilesM = LL / BM;
    gemm_lds_t<2><<<dim3(tilesM * tilesN, 1), 256, 0, stream>>>(
        hsb, w1b, nullptr, LL, 2 * EE, HH, tilesM, 1, nullptr, projh, sg);
  }
  // 2) causal depthwise conv + silu -> h (bf16)
  conv_silu_k<<<dim3(EE / 256, LL / 16), 256, 0, stream>>>(projh, cw, cb, hb);
  // 3) ssm = h @ x_proj_w^T [2048, 160] k=4096, split-K=8 (skinny N)
  {
    int tilesN = (160 + 127) / 128, tilesM = LL / 64;
    gemm_bt<<<dim3(tilesM * tilesN, 8), 256, 0, stream>>>(
        hb, xwb, ssm, LL, 160, EE, tilesN, 8);
  }
  // 4) dt input slice -> bf16
  dtcast_k<<<(LL * RR + 255) / 256, 256, 0, stream>>>(ssm, dtin, LL * RR);
  // 5) dt = softplus(dtin @ dt_proj_w^T + dtb) -> bf16   [2048, 4096] k=128
  {
    int tilesN = EE / BN, tilesM = LL / BM;
    gemm_lds_t<4><<<dim3(tilesM * tilesN, 1), 256, 0, stream>>>(
        dtin, dtwb, nullptr, LL, EE, RR, tilesM, 1, dtb, nullptr, dtb_buf);
  }
  // 6) chunked selective scan + gating -> y (bf16)
  scan_partA<<<dim3(NC, EE / 256), 256, 0, stream>>>(dtb_buf, hb, ssm, Alog,
                                                     Pbuf, Sbuf);
  scan_chunkB<<<EE * NS / 256, 256, 0, stream>>>(Pbuf, Sbuf);
  scan_partC<<<dim3(NC, EE / 256), 256, 0, stream>>>(dtb_buf, hb, ssm, Alog, Dp,
                                                     sg, Sbuf, yb);
  // 7) out = y @ out_proj_w^T [2048, 2048] k=4096, split-K=2
  {
    int tilesN = HH / BN, tilesM = LL / BM;
    gemm_lds_t<1><<<dim3(tilesM * tilesN, 2), 256, 0, stream>>>(
        yb, owb, out, LL, HH, EE, tilesM, 2, nullptr, nullptr, nullptr);
  }
}

// Round 8
// 448.853 us; speedup vs baseline: 1.3044x; 1.3044x over previous
//
#include <hip/hip_runtime.h>

#define LL 2048
#define HH 2048
#define EE 4096
#define NS 16
#define RR 128
#define CT 32            // chunk timesteps
#define NC (LL / CT)     // 64 chunks
#define BM 128
#define BN 128
#define BK 64

typedef __bf16 bf16x8 __attribute__((ext_vector_type(8)));
typedef float f32x4 __attribute__((ext_vector_type(4)));

__device__ __forceinline__ unsigned short f2bf(float f) {
  union { float f; unsigned int u; } v; v.f = f;
  unsigned int r = v.u + 0x7fffu + ((v.u >> 16) & 1u);
  return (unsigned short)(r >> 16);
}

__device__ __forceinline__ float bf2f(unsigned short u) {
  union { unsigned int i; float f; } v;
  v.i = ((unsigned int)u) << 16;
  return v.f;
}

// softplus via native transcendentals only (NO libm log1pf — it's a non-inline
// ocml call that forces VGPR save/restore in high-pressure epilogues; cost R7
// dt_proj 122us)
__device__ __forceinline__ float softplus_fast(float x) {
  if (x > 20.0f) return x;
  float e = __builtin_amdgcn_exp2f(1.44269504f * x);
  return 0.69314718f * __builtin_amdgcn_logf(1.0f + e);
}

__device__ __forceinline__ void async_cp16(const unsigned short* g,
                                           unsigned short* l) {
  __builtin_amdgcn_global_load_lds(
      (const __attribute__((address_space(1))) unsigned int*)g,
      (__attribute__((address_space(3))) unsigned int*)l, 16, 0, 0);
}

// ---------------- fp32 -> bf16 cast (vectorized x4) ----------------
__global__ void cast_bf16_k(const float* __restrict__ in,
                            unsigned short* __restrict__ out, int n4) {
  int i = blockIdx.x * blockDim.x + threadIdx.x;
  if (i >= n4) return;
  float4 v = reinterpret_cast<const float4*>(in)[i];
  ushort4 o;
  o.x = f2bf(v.x); o.y = f2bf(v.y); o.z = f2bf(v.z); o.w = f2bf(v.w);
  reinterpret_cast<ushort4*>(out)[i] = o;
}

// ---------------- zero fill (float4) ----------------
__global__ void zero_k(float* __restrict__ p, int n4) {
  int i = blockIdx.x * blockDim.x + threadIdx.x;
  if (i >= n4) return;
  float4 z; z.x = z.y = z.z = z.w = 0.0f;
  reinterpret_cast<float4*>(p)[i] = z;
}

// ============ LDS-staged bf16 BT-GEMM: C[M,N] = A[M,K] * B[N,K]^T ============
// XCD swizzle: tnInner = bid&7 keeps one B-tile L2-resident per XCD.
// EPI (compile-time): 1 = f32 atomicAdd (split-K)
//                     2 = in_proj: cols<EE -> f32 auxF; cols>=EE -> silu bf16 auxB
//                     4 = +bias[col], softplus, bf16 store to auxB
template <int EPI>
__global__ __launch_bounds__(256) void gemm_lds_t(
    const unsigned short* __restrict__ A,
    const unsigned short* __restrict__ B,
    float* __restrict__ C,
    int M, int N, int K, int tilesM, int splitk,
    const float* __restrict__ bias, float* __restrict__ auxF,
    unsigned short* __restrict__ auxB) {
  __shared__ __align__(16) unsigned short As[BM * BK];
  __shared__ __align__(16) unsigned short Bs[BN * BK];

  int bid = blockIdx.x;
  int tnInner = bid & 7;
  int rest = bid >> 3;
  int tm = rest % tilesM;
  int tnOuter = rest / tilesM;
  int tn = tnOuter * 8 + tnInner;

  int Kslice = K / splitk;
  int k_begin = blockIdx.y * Kslice;
  int k_end = k_begin + Kslice;

  int tid = threadIdx.x;
  int lane = tid & 63;
  int wave = tid >> 6;
  int wm = wave & 1, wn = wave >> 1;
  int m16 = lane & 15, quad = lane >> 4;

  const unsigned short* Ab = A + (size_t)tm * BM * K;
  const unsigned short* Bb = B + (size_t)tn * BN * K;

  int srow[4], sgcb[4];
#pragma unroll
  for (int it = 0; it < 4; ++it) {
    int blk = it * 256 + tid;
    srow[it] = blk >> 3;
    sgcb[it] = (blk & 7) ^ (srow[it] & 7);
  }
  int ldsbase = (tid & ~63) * 8;  // wave-uniform, in ushort units

  f32x4 acc[4][4];
#pragma unroll
  for (int i = 0; i < 4; ++i)
#pragma unroll
    for (int j = 0; j < 4; ++j)
#pragma unroll
      for (int t = 0; t < 4; ++t) acc[i][j][t] = 0.0f;

  for (int k0 = k_begin; k0 < k_end; k0 += BK) {
    __syncthreads();
#pragma unroll
    for (int it = 0; it < 4; ++it)
      async_cp16(Ab + (size_t)srow[it] * K + k0 + sgcb[it] * 8,
                 &As[it * 2048 + ldsbase]);
#pragma unroll
    for (int it = 0; it < 4; ++it)
      async_cp16(Bb + (size_t)srow[it] * K + k0 + sgcb[it] * 8,
                 &Bs[it * 2048 + ldsbase]);
    __syncthreads();
#pragma unroll
    for (int kk = 0; kk < 2; ++kk) {
      bf16x8 a[4], b[4];
#pragma unroll
      for (int i = 0; i < 4; ++i) {
        int rr = wm * 64 + i * 16 + m16;
        int cb = (kk << 2) + quad;
        a[i] = *reinterpret_cast<const bf16x8*>(
            &As[rr * BK + ((cb ^ (rr & 7)) << 3)]);
      }
#pragma unroll
      for (int j = 0; j < 4; ++j) {
        int rr = wn * 64 + j * 16 + m16;
        int cb = (kk << 2) + quad;
        b[j] = *reinterpret_cast<const bf16x8*>(
            &Bs[rr * BK + ((cb ^ (rr & 7)) << 3)]);
      }
#pragma unroll
      for (int i = 0; i < 4; ++i)
#pragma unroll
        for (int j = 0; j < 4; ++j)
          acc[i][j] =
              __builtin_amdgcn_mfma_f32_16x16x32_bf16(a[i], b[j], acc[i][j], 0, 0, 0);
    }
  }

  int rowB = tm * BM + wm * 64;
  int colB = tn * BN + wn * 64;
  if constexpr (EPI == 1) {
#pragma unroll
    for (int i = 0; i < 4; ++i)
#pragma unroll
      for (int j = 0; j < 4; ++j) {
        int col = colB + j * 16 + m16;
        int row0 = rowB + i * 16 + quad * 4;
#pragma unroll
        for (int t = 0; t < 4; ++t)
          atomicAdd(&C[(size_t)(row0 + t) * N + col], acc[i][j][t]);
      }
  } else if constexpr (EPI == 2) {
    if (colB < EE) {
#pragma unroll
      for (int i = 0; i < 4; ++i)
#pragma unroll
        for (int j = 0; j < 4; ++j) {
          int col = colB + j * 16 + m16;
          int row0 = rowB + i * 16 + quad * 4;
#pragma unroll
          for (int t = 0; t < 4; ++t)
            auxF[(size_t)(row0 + t) * EE + col] = acc[i][j][t];
        }
    } else {
#pragma unroll
      for (int i = 0; i < 4; ++i)
#pragma unroll
        for (int j = 0; j < 4; ++j) {
          int cg = colB + j * 16 + m16 - EE;
          int row0 = rowB + i * 16 + quad * 4;
#pragma unroll
          for (int t = 0; t < 4; ++t) {
            float v = acc[i][j][t];
            float s = v / (1.0f + __expf(-v));
            auxB[(size_t)(row0 + t) * EE + cg] = f2bf(s);
          }
        }
    }
  } else {  // EPI == 4: bias + softplus -> bf16
#pragma unroll
    for (int i = 0; i < 4; ++i)
#pragma unroll
      for (int j = 0; j < 4; ++j) {
        int col = colB + j * 16 + m16;
        float bv = bias[col];
        int row0 = rowB + i * 16 + quad * 4;
#pragma unroll
        for (int t = 0; t < 4; ++t) {
          float x = acc[i][j][t] + bv;
          auxB[(size_t)(row0 + t) * EE + col] = f2bf(softplus_fast(x));
        }
      }
  }
}

// ------------- direct (no-LDS) BT-GEMM for skinny N (x_proj) -------------
__global__ __launch_bounds__(256) void gemm_bt(
    const unsigned short* __restrict__ A,
    const unsigned short* __restrict__ B,
    float* __restrict__ C,
    int M, int N, int K, int tilesN, int splitk) {
  int bid = blockIdx.x;
  int groupSize = 8 * tilesN;
  int g = bid / groupSize, r = bid % groupSize;
  int tm = g * 8 + (r & 7);
  int tn = r >> 3;

  int Kslice = K / splitk;
  int k_begin = blockIdx.y * Kslice;
  int k_end = k_begin + Kslice;

  int tid = threadIdx.x;
  int wave = tid >> 6, lane = tid & 63;
  int wm = wave & 1, wn = wave >> 1;
  int m16 = lane & 15, quad = lane >> 4;
  int rowBase = tm * 64 + wm * 32;
  int colBase = tn * 128 + wn * 64;

  const unsigned short* a0p = A + (size_t)(rowBase + m16) * K + quad * 8;
  const unsigned short* a1p = A + (size_t)(rowBase + 16 + m16) * K + quad * 8;
  const unsigned short* bp[4];
  bool bok[4];
#pragma unroll
  for (int j = 0; j < 4; ++j) {
    int col = colBase + j * 16 + m16;
    bok[j] = (col < N);
    bp[j] = B + (size_t)(bok[j] ? col : 0) * K + quad * 8;
  }

  f32x4 acc[2][4];
#pragma unroll
  for (int i = 0; i < 2; ++i)
#pragma unroll
    for (int j = 0; j < 4; ++j)
#pragma unroll
      for (int t = 0; t < 4; ++t) acc[i][j][t] = 0.0f;

  bf16x8 zero8;
#pragma unroll
  for (int t = 0; t < 8; ++t) zero8[t] = (__bf16)0.0f;

  for (int k = k_begin; k < k_end; k += 32) {
    bf16x8 a0 = *reinterpret_cast<const bf16x8*>(a0p + k);
    bf16x8 a1 = *reinterpret_cast<const bf16x8*>(a1p + k);
    bf16x8 b[4];
#pragma unroll
    for (int j = 0; j < 4; ++j)
      b[j] = bok[j] ? *reinterpret_cast<const bf16x8*>(bp[j] + k) : zero8;
#pragma unroll
    for (int j = 0; j < 4; ++j) {
      acc[0][j] = __builtin_amdgcn_mfma_f32_16x16x32_bf16(a0, b[j], acc[0][j], 0, 0, 0);
      acc[1][j] = __builtin_amdgcn_mfma_f32_16x16x32_bf16(a1, b[j], acc[1][j], 0, 0, 0);
    }
  }

#pragma unroll
  for (int i = 0; i < 2; ++i)
#pragma unroll
    for (int j = 0; j < 4; ++j) {
      int col = colBase + j * 16 + m16;
      if (col >= N) continue;
      int row0 = rowBase + i * 16 + quad * 4;
      if (splitk == 1) {
#pragma unroll
        for (int t = 0; t < 4; ++t)
          C[(size_t)(row0 + t) * N + col] = acc[i][j][t];
      } else {
#pragma unroll
        for (int t = 0; t < 4; ++t)
          atomicAdd(&C[(size_t)(row0 + t) * N + col], acc[i][j][t]);
      }
    }
}

// ------- depthwise causal conv (K=4) + bias + silu, register window -------
__global__ __launch_bounds__(256) void conv_silu_k(
    const float* __restrict__ projh, const float* __restrict__ cw,
    const float* __restrict__ cb, unsigned short* __restrict__ hb) {
  int e = blockIdx.x * 256 + threadIdx.x;
  int l0 = blockIdx.y * 16;
  float w0 = cw[e * 4 + 0], w1 = cw[e * 4 + 1];
  float w2 = cw[e * 4 + 2], w3 = cw[e * 4 + 3];
  float bias = cb[e];
  float xm3 = (l0 >= 3) ? projh[(size_t)(l0 - 3) * EE + e] : 0.0f;
  float xm2 = (l0 >= 2) ? projh[(size_t)(l0 - 2) * EE + e] : 0.0f;
  float xm1 = (l0 >= 1) ? projh[(size_t)(l0 - 1) * EE + e] : 0.0f;
#pragma unroll
  for (int t = 0; t < 16; ++t) {
    int l = l0 + t;
    float x0 = projh[(size_t)l * EE + e];
    float acc = bias + w0 * xm3 + w1 * xm2 + w2 * xm1 + w3 * x0;
    float s = acc / (1.0f + __expf(-acc));
    hb[(size_t)l * EE + e] = f2bf(s);
    xm3 = xm2; xm2 = xm1; xm1 = x0;
  }
}

// ---------------- extract dt rows of ssm -> bf16 [L,128] ----------------
__global__ void dtcast_k(const float* __restrict__ ssm,
                         unsigned short* __restrict__ dtin, int n) {
  int i = blockIdx.x * blockDim.x + threadIdx.x;
  if (i >= n) return;
  int l = i >> 7, r = i & 127;
  dtin[i] = f2bf(ssm[l * 160 + r]);
}

// ================= chunked selective scan (16 states per thread) ===========
// dA = exp2(dt * Aa2[n]) with Aa2 = -exp(A_log)*log2e  (one mul + one v_exp)
__global__ __launch_bounds__(256) void scan_partA(
    const unsigned short* __restrict__ dtb, const unsigned short* __restrict__ hb,
    const float* __restrict__ ssm, const float* __restrict__ A_log,
    float* __restrict__ P, float* __restrict__ S) {
  int e = blockIdx.y * 256 + threadIdx.x;
  int c = blockIdx.x;
  float Aa[16];
#pragma unroll
  for (int q = 0; q < 4; ++q) {
    float4 a = reinterpret_cast<const float4*>(&A_log[(size_t)e * NS])[q];
    Aa[q * 4 + 0] = -__expf(a.x) * 1.44269504f;
    Aa[q * 4 + 1] = -__expf(a.y) * 1.44269504f;
    Aa[q * 4 + 2] = -__expf(a.z) * 1.44269504f;
    Aa[q * 4 + 3] = -__expf(a.w) * 1.44269504f;
  }
  float s[16], p[16];
#pragma unroll
  for (int n = 0; n < 16; ++n) { s[n] = 0.0f; p[n] = 1.0f; }
  int l0 = c * CT;
#pragma unroll 2
  for (int t = 0; t < CT; ++t) {
    int l = l0 + t;
    size_t o = (size_t)l * EE + e;
    float dtv = bf2f(dtb[o]);
    float hv = bf2f(hb[o]);
    float Bv[16];
#pragma unroll
    for (int q = 0; q < 4; ++q)
      *reinterpret_cast<float4*>(&Bv[q * 4]) =
          reinterpret_cast<const float4*>(&ssm[(size_t)l * 160 + 128])[q];
    float z = dtv * hv;
#pragma unroll
    for (int n = 0; n < 16; ++n) {
      float dA = __builtin_amdgcn_exp2f(dtv * Aa[n]);
      s[n] = s[n] * dA + z * Bv[n];
      p[n] *= dA;
    }
  }
  size_t base = ((size_t)c * EE + e) * NS;
#pragma unroll
  for (int q = 0; q < 4; ++q) {
    reinterpret_cast<float4*>(&P[base])[q] = *reinterpret_cast<float4*>(&p[q * 4]);
    reinterpret_cast<float4*>(&S[base])[q] = *reinterpret_cast<float4*>(&s[q * 4]);
  }
}

__global__ __launch_bounds__(256) void scan_chunkB(
    const float* __restrict__ P, float* __restrict__ S) {
  int gidx = blockIdx.x * 256 + threadIdx.x;
  float s = 0.0f;
  float pv = P[gidx], sv = S[gidx];
  for (int c = 0; c < NC; ++c) {
    float pn = 0.0f, sn = 0.0f;
    if (c + 1 < NC) {
      size_t i2 = (size_t)(c + 1) * (EE * NS) + gidx;
      pn = P[i2];
      sn = S[i2];
    }
    float s_next = s * pv + sv;
    S[(size_t)c * (EE * NS) + gidx] = s;
    s = s_next;
    pv = pn; sv = sn;
  }
}

__global__ __launch_bounds__(256) void scan_partC(
    const unsigned short* __restrict__ dtb, const unsigned short* __restrict__ hb,
    const float* __restrict__ ssm, const float* __restrict__ A_log,
    const float* __restrict__ Dp, const unsigned short* __restrict__ sg,
    const float* __restrict__ Sinit, unsigned short* __restrict__ yb) {
  int e = blockIdx.y * 256 + threadIdx.x;
  int c = blockIdx.x;
  float Aa[16];
#pragma unroll
  for (int q = 0; q < 4; ++q) {
    float4 a = reinterpret_cast<const float4*>(&A_log[(size_t)e * NS])[q];
    Aa[q * 4 + 0] = -__expf(a.x) * 1.44269504f;
    Aa[q * 4 + 1] = -__expf(a.y) * 1.44269504f;
    Aa[q * 4 + 2] = -__expf(a.z) * 1.44269504f;
    Aa[q * 4 + 3] = -__expf(a.w) * 1.44269504f;
  }
  float Dv = Dp[e];
  float s[16];
  size_t base = ((size_t)c * EE + e) * NS;
#pragma unroll
  for (int q = 0; q < 4; ++q)
    *reinterpret_cast<float4*>(&s[q * 4]) =
        reinterpret_cast<const float4*>(&Sinit[base])[q];
  int l0 = c * CT;
#pragma unroll 2
  for (int t = 0; t < CT; ++t) {
    int l = l0 + t;
    size_t o = (size_t)l * EE + e;
    float dtv = bf2f(dtb[o]);
    float hv = bf2f(hb[o]);
    float Bv[16], Cv[16];
#pragma unroll
    for (int q = 0; q < 4; ++q) {
      *reinterpret_cast<float4*>(&Bv[q * 4]) =
          reinterpret_cast<const float4*>(&ssm[(size_t)l * 160 + 128])[q];
      *reinterpret_cast<float4*>(&Cv[q * 4]) =
          reinterpret_cast<const float4*>(&ssm[(size_t)l * 160 + 144])[q];
    }
    float z = dtv * hv;
    float y = 0.0f;
#pragma unroll
    for (int n = 0; n < 16; ++n) {
      float dA = __builtin_amdgcn_exp2f(dtv * Aa[n]);
      s[n] = s[n] * dA + z * Bv[n];
      y += s[n] * Cv[n];
    }
    float gv = bf2f(sg[o]);  // pre-activated silu(gate)
    float yv = (y + hv * Dv) * gv;
    yb[o] = f2bf(yv);
  }
}

extern "C" void kernel_launch(void* const* d_in, const int* in_sizes, int n_in,
                              void* d_out, int out_size, void* d_ws, size_t ws_size,
                              hipStream_t stream) {
  const float* hs   = (const float*)d_in[0];
  const float* w1   = (const float*)d_in[1];
  const float* cw   = (const float*)d_in[2];
  const float* cb   = (const float*)d_in[3];
  const float* xw   = (const float*)d_in[4];
  const float* dtw  = (const float*)d_in[5];
  const float* dtb  = (const float*)d_in[6];
  const float* Alog = (const float*)d_in[7];
  const float* Dp   = (const float*)d_in[8];
  const float* ow   = (const float*)d_in[9];
  float* out = (float*)d_out;

  char* ws = (char*)d_ws;
  size_t off = 0;
  auto alloc = [&](size_t b) {
    char* p = ws + off;
    off += (b + 255) & ~(size_t)255;
    return p;
  };
  float* projh = (float*)alloc((size_t)LL * EE * 4);                 // 33.5 MB
  unsigned short* sg  = (unsigned short*)alloc((size_t)LL * EE * 2); // 16.8 MB
  unsigned short* hb  = (unsigned short*)alloc((size_t)LL * EE * 2); // 16.8 MB
  unsigned short* dtb_buf = (unsigned short*)alloc((size_t)LL * EE * 2); // 16.8 MB
  unsigned short* w1b = (unsigned short*)alloc((size_t)2 * EE * HH * 2); // 33.5 MB
  unsigned short* hsb = (unsigned short*)alloc((size_t)LL * HH * 2);
  unsigned short* yb  = (unsigned short*)alloc((size_t)LL * EE * 2);
  unsigned short* owb = (unsigned short*)alloc((size_t)HH * EE * 2);
  unsigned short* xwb = (unsigned short*)alloc((size_t)160 * EE * 2);
  float* ssm = (float*)alloc((size_t)LL * 160 * 4);
  unsigned short* dtin = (unsigned short*)alloc((size_t)LL * RR * 2);
  unsigned short* dtwb = (unsigned short*)alloc((size_t)EE * RR * 2);
  float* Pbuf = (float*)alloc((size_t)NC * EE * NS * 4);             // 16.8 MB
  float* Sbuf = (float*)alloc((size_t)NC * EE * NS * 4);             // 16.8 MB

  auto cast = [&](const float* in, unsigned short* o, int nelem) {
    int n4 = nelem / 4;
    cast_bf16_k<<<(n4 + 255) / 256, 256, 0, stream>>>(in, o, n4);
  };
  cast(hs, hsb, LL * HH);
  cast(w1, w1b, 2 * EE * HH);
  cast(xw, xwb, 160 * EE);
  cast(dtw, dtwb, EE * RR);
  cast(ow, owb, HH * EE);
  // zero accumulation targets for split-K atomics
  zero_k<<<(LL * 160 / 4 + 255) / 256, 256, 0, stream>>>(ssm, LL * 160 / 4);
  zero_k<<<(LL * HH / 4 + 255) / 256, 256, 0, stream>>>(out, LL * HH / 4);

  // 1) proj = hs @ in_proj_w^T [2048, 8192]; epilogue: h -> projh f32,
  //    gate -> silu -> sg bf16
  {
    int tilesN = (2 * EE) / BN, tilesM = LL / BM;
    gemm_lds_t<2><<<dim3(tilesM * tilesN, 1), 256, 0, stream>>>(
        hsb, w1b, nullptr, LL, 2 * EE, HH, tilesM, 1, nullptr, projh, sg);
  }
  // 2) causal depthwise conv + silu -> h (bf16)
  conv_silu_k<<<dim3(EE / 256, LL / 16), 256, 0, stream>>>(projh, cw, cb, hb);
  // 3) ssm = h @ x_proj_w^T [2048, 160] k=4096, split-K=8 (skinny N)
  {
    int tilesN = (160 + 127) / 128, tilesM = LL / 64;
    gemm_bt<<<dim3(tilesM * tilesN, 8), 256, 0, stream>>>(
        hb, xwb, ssm, LL, 160, EE, tilesN, 8);
  }
  // 4) dt input slice -> bf16
  dtcast_k<<<(LL * RR + 255) / 256, 256, 0, stream>>>(ssm, dtin, LL * RR);
  // 5) dt = softplus(dtin @ dt_proj_w^T + dtb) -> bf16   [2048, 4096] k=128
  {
    int tilesN = EE / BN, tilesM = LL / BM;
    gemm_lds_t<4><<<dim3(tilesM * tilesN, 1), 256, 0, stream>>>(
        dtin, dtwb, nullptr, LL, EE, RR, tilesM, 1, dtb, nullptr, dtb_buf);
  }
  // 6) chunked selective scan + gating -> y (bf16)
  scan_partA<<<dim3(NC, EE / 256), 256, 0, stream>>>(dtb_buf, hb, ssm, Alog,
                                                     Pbuf, Sbuf);
  scan_chunkB<<<EE * NS / 256, 256, 0, stream>>>(Pbuf, Sbuf);
  scan_partC<<<dim3(NC, EE / 256), 256, 0, stream>>>(dtb_buf, hb, ssm, Alog, Dp,
                                                     sg, Sbuf, yb);
  // 7) out = y @ out_proj_w^T [2048, 2048] k=4096, split-K=2
  {
    int tilesN = HH / BN, tilesM = LL / BM;
    gemm_lds_t<1><<<dim3(tilesM * tilesN, 2), 256, 0, stream>>>(
        yb, owb, out, LL, HH, EE, tilesM, 2, nullptr, nullptr, nullptr);
  }
}